// Round 1
// 213.318 us; speedup vs baseline: 1.0538x; 1.0538x over previous
//
#include <hip/hip_runtime.h>

using sh8 = __attribute__((ext_vector_type(8))) short;
using sh4 = __attribute__((ext_vector_type(4))) short;
using fx4 = __attribute__((ext_vector_type(4))) float;

#define MFMA(a,b,c)   __builtin_amdgcn_mfma_f32_16x16x32_bf16((a),(b),(c),0,0,0)

// RNE cast (epilogue scalars — accuracy-critical path)
__device__ __forceinline__ short f2bf(float f) {
    union { float f; unsigned u; } v; v.f = f;
    return (short)((v.u + 0x7fffu + ((v.u >> 16) & 1u)) >> 16);
}

// Round-half-up pack of two floats to a bf16 pair (3 VALU: 2 add + 1 perm).
__device__ __forceinline__ unsigned bfpair(float lo, float hi) {
    unsigned ul = __float_as_uint(lo) + 0x8000u;
    unsigned uh = __float_as_uint(hi) + 0x8000u;
    return __builtin_amdgcn_perm(uh, ul, 0x07060302);  // [hi.bf16 : lo.bf16]
}

__device__ __forceinline__ sh8 pack8(float4 a, float4 b) {
    union { unsigned u[4]; sh8 s; } r;
    r.u[0] = bfpair(a.x, a.y);
    r.u[1] = bfpair(a.z, a.w);
    r.u[2] = bfpair(b.x, b.y);
    r.u[3] = bfpair(b.z, b.w);
    return r.s;
}

// q scale: D^-0.5 * log2(e) folded together; attn uses exp2 directly.
#define QSCALE 0.18033688011112042f

// ===========================================================================
// Fragment layouts (written by prep_k, consumed barrier-free by attn_k):
//   k_ws : per bh, 256 chunks of 512 shorts. chunk fo = (kb*4+nt)*2+half
//          holds K[key=kb*64+nt*16+llo][d=half*32+lhi*8+j] at lane=lhi*16+llo,
//          slot j.  Group (kb,g) -> 4 consecutive chunks at fo = (kb*2+g)*4.
//   vT_ws: per bh, 256 chunks of 512 shorts. chunk vo = (kb*2+g)*4+dt holds
//          V[key=kb*64+g*32+(i>>2)*16+lhi*4+(i&3)][d=dt*16+llo] at
//          lane=lhi*16+llo, slot i.  (i.e. the K=32 MFMA B-operand
//          permutation matching the P fragment built from two S^T tiles.)
// ===========================================================================

// prep_k: merged qgemm (blocks 0..383) + kvgemm (384..511) + depth_k cast
// (512..1535) + depth_v fragment gather (1536..2047).
__global__ __launch_bounds__(256) void prep_k(const float* __restrict__ x,
                                              const float* __restrict__ Wq,
                                              const float* __restrict__ bq,
                                              const float* __restrict__ Wkv,
                                              const float* __restrict__ bkv,
                                              const float* __restrict__ dk,
                                              const float* __restrict__ dv,
                                              float* __restrict__ ok,
                                              float* __restrict__ ov,
                                              short* __restrict__ q_ws,
                                              short* __restrict__ k_ws,
                                              short* __restrict__ vT_ws)
{
    __shared__ alignas(16) short Al[128 * 40];
    __shared__ alignas(16) short Bl[128 * 40];
    const int blk = blockIdx.x;
    const int t   = threadIdx.x;

    if (blk < 512) {
        // ----- 128x128-tile bf16 GEMM path (qgemm or kvgemm) -----
        const bool isq = (blk < 384);
        const int  i   = isq ? blk : blk - 384;
        const int  nbx = isq ? 6 : 2;
        const int  bm  = (i / nbx) * 128, bn = (i % nbx) * 128;
        const float* Wmat = isq ? Wq : Wkv;

        const int wave = t >> 6, lane = t & 63;
        const int wm   = wave >> 1, wn = wave & 1;
        const int lhi  = lane >> 4, llo = lane & 15;

        const int srow = t >> 1, scol = (t & 1) * 16;
        const float* ap = x    + (size_t)(bm + srow) * 768 + scol;
        const float* bp = Wmat + (size_t)(bn + srow) * 768 + scol;

        fx4 zero = {0.f, 0.f, 0.f, 0.f};
        fx4 acc[4][4];
        #pragma unroll
        for (int a = 0; a < 4; ++a)
            #pragma unroll
            for (int b2 = 0; b2 < 4; ++b2) acc[a][b2] = zero;

        float4 pa0 = *(const float4*)(ap);     float4 pa1 = *(const float4*)(ap + 4);
        float4 pa2 = *(const float4*)(ap + 8); float4 pa3 = *(const float4*)(ap + 12);
        float4 pb0 = *(const float4*)(bp);     float4 pb1 = *(const float4*)(bp + 4);
        float4 pb2 = *(const float4*)(bp + 8); float4 pb3 = *(const float4*)(bp + 12);

        for (int k0 = 0; k0 < 768; k0 += 32) {
            __syncthreads();
            *(sh8*)&Al[srow*40 + scol]     = pack8(pa0, pa1);
            *(sh8*)&Al[srow*40 + scol + 8] = pack8(pa2, pa3);
            *(sh8*)&Bl[srow*40 + scol]     = pack8(pb0, pb1);
            *(sh8*)&Bl[srow*40 + scol + 8] = pack8(pb2, pb3);
            __syncthreads();
            if (k0 + 32 < 768) {
                pa0 = *(const float4*)(ap + k0+32);  pa1 = *(const float4*)(ap + k0+36);
                pa2 = *(const float4*)(ap + k0+40);  pa3 = *(const float4*)(ap + k0+44);
                pb0 = *(const float4*)(bp + k0+32);  pb1 = *(const float4*)(bp + k0+36);
                pb2 = *(const float4*)(bp + k0+40);  pb3 = *(const float4*)(bp + k0+44);
            }
            sh8 af[4], bf[4];
            #pragma unroll
            for (int mt = 0; mt < 4; ++mt)
                af[mt] = *(const sh8*)&Al[(wm*64 + mt*16 + llo)*40 + lhi*8];
            #pragma unroll
            for (int nt = 0; nt < 4; ++nt)
                bf[nt] = *(const sh8*)&Bl[(wn*64 + nt*16 + llo)*40 + lhi*8];
            #pragma unroll
            for (int mt = 0; mt < 4; ++mt)
                #pragma unroll
                for (int nt = 0; nt < 4; ++nt)
                    acc[mt][nt] = MFMA(af[mt], bf[nt], acc[mt][nt]);
        }

        if (isq) {
            #pragma unroll
            for (int nt = 0; nt < 4; ++nt) {
                const int c = bn + wn*64 + nt*16 + llo;
                const float bias = bq[c];
                const int g = c >> 7, h = (c >> 6) & 1, d = c & 63;
                #pragma unroll
                for (int mt = 0; mt < 4; ++mt) {
                    const int m0 = bm + wm*64 + mt*16 + lhi*4;
                    #pragma unroll
                    for (int r = 0; r < 4; ++r) {
                        const int m = m0 + r;
                        const int b = m >> 10, n = m & 1023;
                        const float val = (acc[mt][nt][r] + bias) * QSCALE;
                        q_ws[((size_t)(b*2 + h)*6144 + n*6 + g)*64 + d] = f2bf(val);
                    }
                }
            }
        } else {
            #pragma unroll
            for (int nt = 0; nt < 4; ++nt) {
                const int c = bn + wn*64 + nt*16 + llo;     // 0..255
                const float bias = bkv[c];
                const int s = c >> 7, h = (c >> 6) & 1, d = c & 63;
                #pragma unroll
                for (int mt = 0; mt < 4; ++mt) {
                    const int m0 = bm + wm*64 + mt*16 + lhi*4;
                    const int b = m0 >> 10, n0 = m0 & 1023;
                    float vals[4];
                    #pragma unroll
                    for (int r = 0; r < 4; ++r) vals[r] = acc[mt][nt][r] + bias;
                    const int key = 1024 + n0;              // n0 % 4 == 0
                    if (s == 0) {
                        #pragma unroll
                        for (int r = 0; r < 4; ++r)
                            ok[((size_t)(b*1024 + n0 + r)*2 + h)*64 + d] = vals[r];
                        const int kb_ = key >> 6, nt_ = (key >> 4) & 3;
                        const int half = d >> 5, lhiK = (d >> 3) & 3, j = d & 7;
                        const size_t base = (size_t)(b*2 + h)*131072
                            + (size_t)(((((kb_*4 + nt_)*2 + half)*64) + lhiK*16 + (key & 15))*8 + j);
                        #pragma unroll
                        for (int r = 0; r < 4; ++r)
                            k_ws[base + r*8] = f2bf(vals[r]);
                    } else {
                        #pragma unroll
                        for (int r = 0; r < 4; ++r)
                            ov[((size_t)(b*1024 + n0 + r)*2 + h)*64 + d] = vals[r];
                        const int kb_ = key >> 6, g_ = (key >> 5) & 1, k5 = key & 31;
                        const int half5 = k5 >> 4, lhi5 = (k5 >> 2) & 3;   // j5 = r
                        const int dt_ = d >> 4, llov = d & 15;
                        short4 pk = make_short4(f2bf(vals[0]), f2bf(vals[1]),
                                                f2bf(vals[2]), f2bf(vals[3]));
                        const size_t base = (size_t)(b*2 + h)*131072
                            + (size_t)(((((kb_*2 + g_)*4 + dt_)*64) + lhi5*16 + llov)*8 + half5*4);
                        *(short4*)&vT_ws[base] = pk;
                    }
                }
            }
        }
    } else if (blk < 1536) {
        // ----- depth_k cast: [b][tt][h][d] fp32 -> k_ws fragment layout -----
        const size_t idx4 = ((size_t)(blk - 512) * 256 + t) * 4;
        const int b  = (int)(idx4 >> 17);
        const int rm = (int)(idx4 & 131071);
        const int tt = rm >> 7, h = (rm >> 6) & 1, d = rm & 63;   // d % 4 == 0
        float4 v = *(const float4*)(dk + idx4);
        short4 pk = make_short4(f2bf(v.x), f2bf(v.y), f2bf(v.z), f2bf(v.w));
        const int kb_ = tt >> 6, nt_ = (tt >> 4) & 3, lloK = tt & 15;
        const int half = d >> 5, lhiK = (d >> 3) & 3, j = d & 7;  // j in {0,4}
        const size_t addr = (size_t)(b*2 + h)*131072
            + (size_t)(((((kb_*4 + nt_)*2 + half)*64) + lhiK*16 + lloK)*8 + j);
        *(short4*)&k_ws[addr] = pk;
    } else {
        // ----- depth_v: direct gather into V fragment layout -----
        const int unit = (blk - 1536)*4 + (t >> 6);   // 0..2047
        const int lane = t & 63, lhi = lane >> 4, llo = lane & 15;
        const int dt_ = unit & 3, g_ = (unit >> 2) & 1;
        const int kb_ = (unit >> 3) & 15, bh = unit >> 7;
        const int b = bh >> 1, h = bh & 1;
        const float* s0 = dv
            + ((size_t)((b*1024 + kb_*64 + g_*32 + lhi*4)*2 + h))*64 + dt_*16 + llo;
        union { short s[8]; sh8 v8; } o;
        #pragma unroll
        for (int jj = 0; jj < 4; ++jj) o.s[jj]     = f2bf(s0[(size_t)jj * 128]);
        #pragma unroll
        for (int jj = 0; jj < 4; ++jj) o.s[4 + jj] = f2bf(s0[(size_t)(16 + jj) * 128]);
        *(sh8*)&vT_ws[((size_t)bh*256 + (kb_*2 + g_)*4 + dt_)*512 + lane*8] = o.v8;
    }
}

// ---------------------------------------------------------------------------
// Attention v6: barrier-free, LDS-free.  K/V fragments are read directly from
// the pre-permuted workspace as fully-coalesced b128 loads (L1/L2-resident:
// 512 KB per bh shared by 32 blocks).  PV uses full-rate 16x16x32 MFMA with
// the P fragment packed across two adjacent S^T tiles; row sums via a
// ones-column MFMA land the softmax denominator in the exact D-layout rows
// the epilogue needs (no shuffles, no VALU add chain).
// ---------------------------------------------------------------------------
__global__ __launch_bounds__(256) void attn_k(const short* __restrict__ q_ws,
                                              const short* __restrict__ k_ws,
                                              const short* __restrict__ vT_ws,
                                              short* __restrict__ o_ws)
{
    const int t    = threadIdx.x;
    const int wave = t >> 6, lane = t & 63;
    const int lhi  = lane >> 4, llo = lane & 15;
    const int bh   = blockIdx.y;
    const int b    = bh >> 1, h = bh & 1;
    const int qt   = blockIdx.x;               // 192-q tile index

    const short* qb = q_ws + ((size_t)bh*6144 + qt*192 + wave*48) * 64;
    sh8 qf[3][2];
    #pragma unroll
    for (int s = 0; s < 3; ++s) {
        qf[s][0] = *(const sh8*)(qb + (s*16 + llo)*64 + lhi*8);
        qf[s][1] = *(const sh8*)(qb + (s*16 + llo)*64 + lhi*8 + 32);
    }

    const short* kp = k_ws  + (size_t)bh*131072 + lane*8;
    const short* vp = vT_ws + (size_t)bh*131072 + lane*8;

    fx4 zero = {0.f, 0.f, 0.f, 0.f};
    fx4 oacc[3][4];
    fx4 lacc[3];
    #pragma unroll
    for (int s = 0; s < 3; ++s) {
        lacc[s] = zero;
        #pragma unroll
        for (int dt = 0; dt < 4; ++dt) oacc[s][dt] = zero;
    }

    union { unsigned u[4]; sh8 s8; } onesu;
    onesu.u[0] = onesu.u[1] = onesu.u[2] = onesu.u[3] = 0x3F803F80u;  // bf16 1.0 x8
    const sh8 ones = onesu.s8;

    // group it = kb*2+g reads 4 consecutive K chunks and 4 consecutive V
    // chunks at chunk index it*4 (offset it*2048 shorts, lane offset baked in).
    auto loadg = [&](sh8& K0, sh8& K1, sh8& K2, sh8& K3,
                     sh8& V0, sh8& V1, sh8& V2, sh8& V3, int it) {
        const short* kq = kp + (size_t)it * 2048;
        const short* vq = vp + (size_t)it * 2048;
        K0 = *(const sh8*)(kq);        K1 = *(const sh8*)(kq + 512);
        K2 = *(const sh8*)(kq + 1024); K3 = *(const sh8*)(kq + 1536);
        V0 = *(const sh8*)(vq);        V1 = *(const sh8*)(vq + 512);
        V2 = *(const sh8*)(vq + 1024); V3 = *(const sh8*)(vq + 1536);
    };

    auto compg = [&](sh8 K0, sh8 K1, sh8 K2, sh8 K3,
                     sh8 V0, sh8 V1, sh8 V2, sh8 V3) {
        #pragma unroll
        for (int s = 0; s < 3; ++s) {
            fx4 stA = MFMA(K0, qf[s][0], zero); stA = MFMA(K1, qf[s][1], stA);
            fx4 stB = MFMA(K2, qf[s][0], zero); stB = MFMA(K3, qf[s][1], stB);
            float pa0 = __builtin_amdgcn_exp2f(stA[0]);
            float pa1 = __builtin_amdgcn_exp2f(stA[1]);
            float pa2 = __builtin_amdgcn_exp2f(stA[2]);
            float pa3 = __builtin_amdgcn_exp2f(stA[3]);
            float pb0 = __builtin_amdgcn_exp2f(stB[0]);
            float pb1 = __builtin_amdgcn_exp2f(stB[1]);
            float pb2 = __builtin_amdgcn_exp2f(stB[2]);
            float pb3 = __builtin_amdgcn_exp2f(stB[3]);
            union { unsigned u[4]; sh8 s8; } pu;
            pu.u[0] = bfpair(pa0, pa1);
            pu.u[1] = bfpair(pa2, pa3);
            pu.u[2] = bfpair(pb0, pb1);
            pu.u[3] = bfpair(pb2, pb3);
            lacc[s]    = MFMA(pu.s8, ones, lacc[s]);
            oacc[s][0] = MFMA(pu.s8, V0, oacc[s][0]);
            oacc[s][1] = MFMA(pu.s8, V1, oacc[s][1]);
            oacc[s][2] = MFMA(pu.s8, V2, oacc[s][2]);
            oacc[s][3] = MFMA(pu.s8, V3, oacc[s][3]);
        }
    };

    sh8 xk0, xk1, xk2, xk3, xv0, xv1, xv2, xv3;
    sh8 yk0, yk1, yk2, yk3, yv0, yv1, yv2, yv3;

    loadg(xk0, xk1, xk2, xk3, xv0, xv1, xv2, xv3, 0);
    for (int it = 0; it < 64; it += 2) {
        loadg(yk0, yk1, yk2, yk3, yv0, yv1, yv2, yv3, it + 1);
        compg(xk0, xk1, xk2, xk3, xv0, xv1, xv2, xv3);
        loadg(xk0, xk1, xk2, xk3, xv0, xv1, xv2, xv3, (it + 2 < 64) ? it + 2 : 63);
        compg(yk0, yk1, yk2, yk3, yv0, yv1, yv2, yv3);
    }

    // epilogue: lacc[s][r] already holds the full denominator for q-row
    // s*16 + lhi*4 + r (identical across llo) — no shuffles needed.
    #pragma unroll
    for (int s = 0; s < 3; ++s) {
        #pragma unroll
        for (int r = 0; r < 4; ++r) {
            const float iq = 1.0f / lacc[s][r];
            const int qi = qt*192 + wave*48 + s*16 + lhi*4 + r;
            const int n = qi / 6, g = qi % 6;
            short* orow = o_ws + ((size_t)(b*1024 + n))*768 + g*128 + h*64;
            #pragma unroll
            for (int dt = 0; dt < 4; ++dt)
                orow[dt*16 + llo] = f2bf(oacc[s][dt][r] * iq);
        }
    }
}

// ---------------------------------------------------------------------------
// proj GEMM: out = o(8192x768,bf16) @ Wproj^T + bproj -> fp32.  grid (6, 64).
// ---------------------------------------------------------------------------
__global__ __launch_bounds__(256) void projgemm_k(const short* __restrict__ o_ws,
                                                  const float* __restrict__ Wp,
                                                  const float* __restrict__ bpj,
                                                  float* __restrict__ out)
{
    __shared__ alignas(16) short Al[128 * 40];
    __shared__ alignas(16) short Bl[128 * 40];
    const int t    = threadIdx.x;
    const int wave = t >> 6, lane = t & 63;
    const int wm   = wave >> 1, wn = wave & 1;
    const int lhi  = lane >> 4, llo = lane & 15;
    const int bm   = blockIdx.y * 128, bn = blockIdx.x * 128;

    const int srow = t >> 1, scol = (t & 1) * 16;
    const short* ap = o_ws + (size_t)(bm + srow) * 768 + scol;
    const float* bp = Wp   + (size_t)(bn + srow) * 768 + scol;

    fx4 zero = {0.f, 0.f, 0.f, 0.f};
    fx4 acc[4][4];
    #pragma unroll
    for (int i = 0; i < 4; ++i)
        #pragma unroll
        for (int j = 0; j < 4; ++j) acc[i][j] = zero;

    sh8 qa0 = *(const sh8*)(ap), qa1 = *(const sh8*)(ap + 8);
    float4 pb0 = *(const float4*)(bp);     float4 pb1 = *(const float4*)(bp + 4);
    float4 pb2 = *(const float4*)(bp + 8); float4 pb3 = *(const float4*)(bp + 12);

    for (int k0 = 0; k0 < 768; k0 += 32) {
        __syncthreads();
        *(sh8*)&Al[srow*40 + scol]     = qa0;
        *(sh8*)&Al[srow*40 + scol + 8] = qa1;
        *(sh8*)&Bl[srow*40 + scol]     = pack8(pb0, pb1);
        *(sh8*)&Bl[srow*40 + scol + 8] = pack8(pb2, pb3);
        __syncthreads();
        if (k0 + 32 < 768) {
            qa0 = *(const sh8*)(ap + k0+32);  qa1 = *(const sh8*)(ap + k0+40);
            pb0 = *(const float4*)(bp + k0+32);  pb1 = *(const float4*)(bp + k0+36);
            pb2 = *(const float4*)(bp + k0+40);  pb3 = *(const float4*)(bp + k0+44);
        }
        sh8 af[4], bf[4];
        #pragma unroll
        for (int mt = 0; mt < 4; ++mt)
            af[mt] = *(const sh8*)&Al[(wm*64 + mt*16 + llo)*40 + lhi*8];
        #pragma unroll
        for (int nt = 0; nt < 4; ++nt)
            bf[nt] = *(const sh8*)&Bl[(wn*64 + nt*16 + llo)*40 + lhi*8];
        #pragma unroll
        for (int mt = 0; mt < 4; ++mt)
            #pragma unroll
            for (int nt = 0; nt < 4; ++nt)
                acc[mt][nt] = MFMA(af[mt], bf[nt], acc[mt][nt]);
    }

    #pragma unroll
    for (int nt = 0; nt < 4; ++nt) {
        const int c = bn + wn*64 + nt*16 + llo;
        const float bias = bpj[c];
        #pragma unroll
        for (int mt = 0; mt < 4; ++mt) {
            const int m0 = bm + wm*64 + mt*16 + lhi*4;
            #pragma unroll
            for (int r = 0; r < 4; ++r)
                out[(size_t)(m0 + r)*768 + c] = acc[mt][nt][r] + bias;
        }
    }
}

// ---------------------------------------------------------------------------
extern "C" void kernel_launch(void* const* d_in, const int* in_sizes, int n_in,
                              void* d_out, int out_size, void* d_ws, size_t ws_size,
                              hipStream_t stream)
{
    const float* x   = (const float*)d_in[0];
    const float* dk  = (const float*)d_in[1];
    const float* dv  = (const float*)d_in[2];
    const float* Wq  = (const float*)d_in[3];
    const float* bq  = (const float*)d_in[4];
    const float* Wkv = (const float*)d_in[5];
    const float* bkv = (const float*)d_in[6];
    const float* Wp  = (const float*)d_in[7];
    const float* bpj = (const float*)d_in[8];

    float* out = (float*)d_out;
    float* ok  = out + 6291456;            // k output (8,1024,2,64)
    float* ov  = out + 7340032;            // v output

    char* ws = (char*)d_ws;
    short* q_ws  = (short*)(ws);                    // 12,582,912 B
    short* k_ws  = (short*)(ws + 12582912);         //  4,194,304 B (frag layout)
    short* vT_ws = (short*)(ws + 16777216);         //  4,194,304 B (frag layout)
    short* o_ws  = (short*)(ws + 20971520);         // 12,582,912 B  (32 MiB total)

    prep_k     <<<dim3(2048),   256, 0, stream>>>(x, Wq, bq, Wkv, bkv, dk, dv,
                                                  ok, ov, q_ws, k_ws, vT_ws);
    attn_k     <<<dim3(32, 16), 256, 0, stream>>>(q_ws, k_ws, vT_ws, o_ws);
    projgemm_k <<<dim3(6, 64),  256, 0, stream>>>(o_ws, Wp, bpj, out);
}